// Round 1
// baseline (42.319 us; speedup 1.0000x reference)
//
#include <hip/hip_runtime.h>

// Problem constants (from reference)
#define N_IDEAS 5
#define N_EXPERTS 10
#define OUT_DIM 784          // 28*28
#define CHUNKS 196           // OUT_DIM / 4 (float4 chunks per sample)
#define BATCH 32768

// One thread per float4 output chunk. Write-BW bound: ~103 MB of output.
// W (157 KB) and b (31 KB) are L2-resident; x/label loads broadcast across
// the 196 consecutive threads sharing a sample.
__global__ __launch_bounds__(256) void moe_gather_gemv_kernel(
    const float* __restrict__ x,      // [B, 5]
    const int* __restrict__ labels,   // [B]
    const float* __restrict__ W,      // [E, 784, 5]
    const float* __restrict__ b,      // [E, 784]
    float4* __restrict__ out,         // [B*196] float4 view of [B,784]
    int total)                        // B * CHUNKS
{
    int idx = blockIdx.x * blockDim.x + threadIdx.x;
    const int stride = gridDim.x * blockDim.x;
    for (; idx < total; idx += stride) {
        const int s = idx / CHUNKS;          // sample (magic-number div)
        const int c = idx - s * CHUNKS;      // float4 chunk within the row
        const int e = labels[s];

        // x row: 5 scalars, same address for 196 consecutive threads -> broadcast
        const float* xp = x + (size_t)s * N_IDEAS;
        const float x0 = xp[0], x1 = xp[1], x2 = xp[2], x3 = xp[3], x4 = xp[4];

        // W rows for this chunk: 4 rows x 5 floats, contiguous 80 B
        const float* Wp = W + ((size_t)e * OUT_DIM + (size_t)c * 4) * N_IDEAS;
        const float* bp = b + (size_t)e * OUT_DIM + (size_t)c * 4;

        float acc[4];
#pragma unroll
        for (int j = 0; j < 4; ++j) {
            const float* w = Wp + j * N_IDEAS;
            acc[j] = bp[j] + w[0] * x0 + w[1] * x1 + w[2] * x2
                           + w[3] * x3 + w[4] * x4;
        }

        float4 r;
        r.x = acc[0]; r.y = acc[1]; r.z = acc[2]; r.w = acc[3];
        out[idx] = r;
    }
}

extern "C" void kernel_launch(void* const* d_in, const int* in_sizes, int n_in,
                              void* d_out, int out_size, void* d_ws, size_t ws_size,
                              hipStream_t stream) {
    const float* x      = (const float*)d_in[0];
    const int*   labels = (const int*)d_in[1];
    const float* W      = (const float*)d_in[2];
    const float* b      = (const float*)d_in[3];
    float4* out = (float4*)d_out;

    const int total = BATCH * CHUNKS;        // 6,422,528 float4 chunks
    const int block = 256;
    // Memory-bound: cap grid at ~2048 blocks and grid-stride (Guideline 11).
    int grid = 2048;

    moe_gather_gemv_kernel<<<grid, block, 0, stream>>>(x, labels, W, b, out, total);
}

// Round 2
// 27.189 us; speedup vs baseline: 1.5565x; 1.5565x over previous
//
#include <hip/hip_runtime.h>

// Problem constants (from reference)
#define N_IDEAS 5
#define N_EXPERTS 10
#define OUT_DIM 784          // 28*28
#define CHUNKS 196           // OUT_DIM / 4 (float4 chunks per sample)
#define BATCH 32768

// Tiling: 7 chunk-tiles of 28 chunks (112 outputs) each; 256 sample-groups
// of 128 samples. Each block stages its W/b tile + x/labels slab in LDS,
// then the hot loop does LDS reads + 20 FMA + ONE global_store_dwordx4.
#define CTILE 28             // chunks per tile (196 = 7*28)
#define NTILES 7
#define SPB 128              // samples per block (32768 = 256*128)
#define BLOCK 256
#define ITERS ((SPB * CTILE) / BLOCK)   // = 14, exact

__global__ __launch_bounds__(BLOCK) void moe_gather_gemv_lds(
    const float* __restrict__ x,      // [B, 5]
    const int* __restrict__ labels,   // [B]
    const float* __restrict__ W,      // [E, 784, 5]
    const float* __restrict__ b,      // [E, 784]
    float4* __restrict__ out)         // [B*196] float4 view of [B,784]
{
    // LDS: W-tile 5600 f (22.4KB) + b-tile 1120 f (4.5KB) + x 640 f (2.5KB)
    //      + labels 128 i (0.5KB)  = ~29.9 KB
    __shared__ float Wl[N_EXPERTS * CTILE * 20];   // [e][c][20]
    __shared__ float bl[N_EXPERTS * CTILE * 4];    // [e][c][4]
    __shared__ float xl[SPB * N_IDEAS];            // [s][5]
    __shared__ int   ll[SPB];                      // [s]

    const int tid = threadIdx.x;
    const int sg  = blockIdx.x;       // sample group: samples [sg*128, +128)
    const int ct  = blockIdx.y;       // chunk tile:   chunks  [ct*28,  +28)

    // ---- stage W tile: per expert e, global floats [e*3920 + ct*560, +560)
    {
        const float4* Wg = (const float4*)W;            // W is 16B-aligned
        float4* Wl4 = (float4*)Wl;
        for (int i = tid; i < N_EXPERTS * 140; i += BLOCK) {   // 560/4=140
            const int e = i / 140;
            const int r = i - e * 140;
            Wl4[e * 140 + r] = Wg[e * 980 + ct * 140 + r];     // 3920/4=980
        }
        const float4* bg = (const float4*)b;
        float4* bl4 = (float4*)bl;
        for (int i = tid; i < N_EXPERTS * CTILE; i += BLOCK) { // 112/4=28
            const int e = i / CTILE;
            const int r = i - e * CTILE;
            bl4[e * CTILE + r] = bg[e * 196 + ct * CTILE + r]; // 784/4=196
        }
        const float4* xg = (const float4*)x;
        float4* xl4 = (float4*)xl;
        for (int i = tid; i < (SPB * N_IDEAS) / 4; i += BLOCK) // 160 f4
            xl4[i] = xg[sg * 160 + i];                          // 640 f / blk
        const int4* lg = (const int4*)labels;
        int4* ll4 = (int4*)ll;
        if (tid < SPB / 4)
            ll4[tid] = lg[sg * (SPB / 4) + tid];
    }
    __syncthreads();

    // ---- hot loop: 14 exact iterations, one float4 store each
    const size_t outBase = (size_t)sg * SPB * CHUNKS + (size_t)ct * CTILE;
#pragma unroll
    for (int k = 0; k < ITERS; ++k) {
        const int i   = tid + k * BLOCK;        // 0 .. 3583
        const int s_l = i / CTILE;              // local sample 0..127
        const int c_l = i - s_l * CTILE;        // local chunk  0..27
        const int e   = ll[s_l];

        const float* xp = &xl[s_l * N_IDEAS];
        const float x0 = xp[0], x1 = xp[1], x2 = xp[2], x3 = xp[3], x4 = xp[4];

        // 20 W floats for this chunk: 5x ds_read_b128 (80B, 16B-aligned)
        const float4* wp = (const float4*)&Wl[(e * CTILE + c_l) * 20];
        const float4 w0 = wp[0], w1 = wp[1], w2 = wp[2], w3 = wp[3], w4 = wp[4];
        const float4* bp = (const float4*)&bl[(e * CTILE + c_l) * 4];
        const float4 bb = bp[0];

        float4 r;
        r.x = bb.x + w0.x*x0 + w0.y*x1 + w0.z*x2 + w0.w*x3 + w1.x*x4;
        r.y = bb.y + w1.y*x0 + w1.z*x1 + w1.w*x2 + w2.x*x3 + w2.y*x4;
        r.z = bb.z + w2.z*x0 + w2.w*x1 + w3.x*x2 + w3.y*x3 + w3.z*x4;
        r.w = bb.w + w3.w*x0 + w4.x*x1 + w4.y*x2 + w4.z*x3 + w4.w*x4;

        out[outBase + (size_t)s_l * CHUNKS + c_l] = r;
    }
}

extern "C" void kernel_launch(void* const* d_in, const int* in_sizes, int n_in,
                              void* d_out, int out_size, void* d_ws, size_t ws_size,
                              hipStream_t stream) {
    const float* x      = (const float*)d_in[0];
    const int*   labels = (const int*)d_in[1];
    const float* W      = (const float*)d_in[2];
    const float* b      = (const float*)d_in[3];
    float4* out = (float4*)d_out;

    dim3 grid(BATCH / SPB, NTILES);   // 256 x 7 = 1792 blocks
    moe_gather_gemv_lds<<<grid, dim3(BLOCK), 0, stream>>>(x, labels, W, b, out);
}